// Round 13
// baseline (149.050 us; speedup 1.0000x reference)
//
#include <hip/hip_runtime.h>
#include <hip/hip_bf16.h>
#include <math.h>

typedef _Float16 half8 __attribute__((ext_vector_type(8)));
typedef __fp16 fp16x2 __attribute__((ext_vector_type(2)));
typedef float f32x4 __attribute__((ext_vector_type(4)));
typedef unsigned short u16x4 __attribute__((ext_vector_type(4)));
typedef unsigned short u16x8 __attribute__((ext_vector_type(8)));

#define B_   8
#define C_   512
#define H_   96
#define W_   96
#define HW   9216
#define K_   64
#define PH   12
#define PW   12
#define NT   64     // n-tile per block in k_main (256B rows = 2 lines exact)
#define CCH  64     // c-chunk (8 chunks, 8 barriers)
#define NBLK 144    // n-blocks per batch (1152 blocks = 4.5/CU)

// ws layout (bytes). candV/candN alias the dead `part` region.
#define OFF_PARTIAL 0u                    // float[8][73728]  -- dead after k_selgather
#define OFF_CANDV   0u                    // float[512*NBLK]
#define OFF_CANDN   294912u               // int[512*NBLK]
#define OFF_DESCH   2359296u              // _Float16[B*K*C]  ([b][k][c], hi)
#define OFF_DESCL   2883584u              // _Float16[B*K*C]  (lo * 2048)
#define OFF_ROWA    3407872u              // int[512]
#define OFF_COLA    3409920u              // int[512]

// k_main LDS (halfwords). One buffer = FBT only:
//   HI: [nt:4][csub:2][perm(cc):32][nn:16] = 4096 hw ; LO at +4096. BUFHW=8192.
#define FBT_LO 4096
#define BUFHW  8192

// ---------------- kernel 1: partial channel sums (float4) ----------------
__global__ __launch_bounds__(128) void k_partial(const float* __restrict__ A,
                                                 float* __restrict__ part) {
    int idx4 = blockIdx.x * 128 + threadIdx.x;
    int chunk = blockIdx.y;
    int b = idx4 / (HW / 4), hw4 = idx4 - b * (HW / 4);
    const float* p = A + ((size_t)(b * C_ + chunk * 64)) * HW + hw4 * 4;
    float4 s = make_float4(0.f, 0.f, 0.f, 0.f);
#pragma unroll
    for (int i = 0; i < 64; ++i) {
        float4 v = *(const float4*)&p[(size_t)i * HW];
        s.x += v.x; s.y += v.y; s.z += v.z; s.w += v.w;
    }
    *(float4*)&part[chunk * (B_ * HW) + b * HW + hw4 * 4] = s;
}

// ---------------- kernel 2: argmax select + split-f16 descriptor gather ----
__global__ void k_selgather(const float* __restrict__ part, const float* __restrict__ A,
                            int* __restrict__ rowA, int* __restrict__ colA,
                            _Float16* __restrict__ descH, _Float16* __restrict__ descL) {
    int k = blockIdx.x, b = blockIdx.y, lane = threadIdx.x;
    int gi = k >> 3, gj = k & 7;
    float bv = -1e30f; int bp = 1 << 20;
    for (int p = lane; p < PH * PW; p += 64) {
        int lr = p / PW, lc = p - lr * PW;
        int hw = (gi * PH + lr) * W_ + gj * PW + lc;
        float v = 0.f;
#pragma unroll
        for (int ch = 0; ch < 8; ++ch) v += part[ch * (B_ * HW) + b * HW + hw];
        if (v > bv || (v == bv && p < bp)) { bv = v; bp = p; }
    }
    for (int m = 1; m < 64; m <<= 1) {
        float ov = __shfl_xor(bv, m);
        int   op = __shfl_xor(bp, m);
        if (ov > bv || (ov == bv && op < bp)) { bv = ov; bp = op; }
    }
    int lr = bp / PW, lc = bp - lr * PW;
    int r = gi * PH + lr, c = gj * PW + lc;
    int flat = r * W_ + c;
    if (lane == 0) { rowA[b * K_ + k] = r; colA[b * K_ + k] = c; }
#pragma unroll
    for (int i = 0; i < 8; ++i) {
        int cc = i * 64 + lane;
        float v = A[((size_t)(b * C_ + cc)) * HW + flat];
        _Float16 h = (_Float16)v;
        _Float16 lo = (_Float16)((v - (float)h) * 2048.f);
        size_t o = ((size_t)(b * K_ + k)) * C_ + cc;
        descH[o] = h; descL[o] = lo;
    }
}

// ---------------- kernel 3: MFMA cross GEMM + fused argmin ----------------
// grid (144, 8), block 256 (4 waves). Wave w owns k-tile w*16..+15; 4 n-tiles
// of 16 each; K-chunks of 64 c (2 MFMA sub-chunks of 32). fp32-split f16 MFMA.
// fb: global->regs (depth-2 A/B sets)->convert->tr-layout LDS (dbuf).
// desc (A-frags): register-prefetched from global (L2-resident), NO LDS.
__global__ __launch_bounds__(256, 4) void k_main(const float* __restrict__ FB,
                                                 const _Float16* __restrict__ descH,
                                                 const _Float16* __restrict__ descL,
                                                 float* __restrict__ candV,
                                                 int* __restrict__ candN) {
    __shared__ __attribute__((aligned(16))) unsigned short smem_us[2 * BUFHW];
    int b = blockIdx.y, nb = blockIdx.x * NT;
    int tid = threadIdx.x;
    int l = tid & 63;
    int w = tid >> 6;                          // wave id 0..3 (k-tile)
    const size_t baseB = (size_t)b * C_ * HW + nb;

    // fb staging map (all 256 threads): o = n-octet 0..7, cr = c-row 0..31
    const int o_ = tid & 7;
    const int cr = tid >> 3;
    const int nt_ = o_ >> 1, oct_ = o_ & 1;
    // precomputed store base (hw, within-buffer) for csub 0; csub1 = +512
    const int stb = nt_ * 1024 + ((cr >> 2) & 1) * 256 + (cr >> 3) * 64
                    + (cr & 3) * 16 + oct_ * 8;

    f32x4 accH[4], accX[4];
#pragma unroll
    for (int nt = 0; nt < 4; ++nt) {
        accH[nt] = (f32x4){0.f, 0.f, 0.f, 0.f};
        accX[nt] = (f32x4){0.f, 0.f, 0.f, 0.f};
    }
    float sq[8];
#pragma unroll
    for (int j = 0; j < 8; ++j) sq[j] = 0.f;

    // named staging sets: FB A/B (chunk parity), desc single set (depth-1)
    float4 Aa0, Aa1, Ab0, Ab1;
    float4 Ba0, Ba1, Bb0, Bb1;
    u16x8 dH0, dH1, dL0, dL1;

#define LOADFB(S, c0)                                                         \
    do {                                                                      \
        const float* p0 = &FB[baseB + (size_t)((c0) + cr) * HW + o_ * 8];     \
        S##a0 = *(const float4*)p0; S##a1 = *(const float4*)(p0 + 4);         \
        const float* p1 = &FB[baseB + (size_t)((c0) + cr + 32) * HW + o_ * 8];\
        S##b0 = *(const float4*)p1; S##b1 = *(const float4*)(p1 + 4);         \
    } while (0)

#define LOADDESC(c0)                                                          \
    do {                                                                      \
        size_t o = ((size_t)(b * K_) + w * 16 + (l & 15)) * C_ + (c0) + (l >> 4) * 8; \
        dH0 = *(const u16x8*)&descH[o];                                       \
        dH1 = *(const u16x8*)&descH[o + 32];                                  \
        dL0 = *(const u16x8*)&descL[o];                                       \
        dL1 = *(const u16x8*)&descL[o + 32];                                  \
    } while (0)

#define CVT8(va, vb, hofs)                                                    \
    do {                                                                      \
        union { fp16x2 p[4]; half8 h; } hh, ll;                               \
        float vv[8] = {va.x, va.y, va.z, va.w, vb.x, vb.y, vb.z, vb.w};       \
        _Pragma("unroll")                                                     \
        for (int j = 0; j < 4; ++j) {                                         \
            float a = vv[2 * j], bq = vv[2 * j + 1];                          \
            fp16x2 hp = __builtin_amdgcn_cvt_pkrtz(a, bq);                    \
            float ha = (float)hp[0], hb = (float)hp[1];                       \
            fp16x2 lp = __builtin_amdgcn_cvt_pkrtz((a - ha) * 2048.f,         \
                                                   (bq - hb) * 2048.f);       \
            hh.p[j] = hp; ll.p[j] = lp;                                       \
            sq[2 * j]     = fmaf(a, a, sq[2 * j]);                            \
            sq[2 * j + 1] = fmaf(bq, bq, sq[2 * j + 1]);                      \
        }                                                                     \
        *(half8*)&smem_us[(hofs)] = hh.h;                                     \
        *(half8*)&smem_us[(hofs) + FBT_LO] = ll.h;                            \
    } while (0)

#define WRITEFB(S, bufhw)                                                     \
    do {                                                                      \
        CVT8(S##a0, S##a1, (bufhw) + stb);         /* csub 0 (c = cr)    */   \
        CVT8(S##b0, S##b1, (bufhw) + stb + 512);   /* csub 1 (c = cr+32) */   \
    } while (0)

    const unsigned lds0 = (unsigned)(size_t)&smem_us[0];

#define TRQ(d0, d1, d2, d3, addr)                                             \
    asm volatile("ds_read_b64_tr_b16 %0, %1"             : "=v"(d0) : "v"(addr)); \
    asm volatile("ds_read_b64_tr_b16 %0, %1 offset:512"  : "=v"(d1) : "v"(addr)); \
    asm volatile("ds_read_b64_tr_b16 %0, %1 offset:8192" : "=v"(d2) : "v"(addr)); \
    asm volatile("ds_read_b64_tr_b16 %0, %1 offset:8704" : "=v"(d3) : "v"(addr));

#define WAIT4 asm volatile("s_waitcnt lgkmcnt(4)" ::: "memory");              \
              __builtin_amdgcn_sched_barrier(0);
#define WAIT0 asm volatile("s_waitcnt lgkmcnt(0)" ::: "memory");              \
              __builtin_amdgcn_sched_barrier(0);

#define MFMA3(nt, AH, AL, h0_, h1_, l0_, l1_)                                 \
    do {                                                                      \
        union { u16x4 q[2]; half8 h; } bh, bl;                                \
        union { u16x8 u; half8 h; } ah, al;                                   \
        bh.q[0] = h0_; bh.q[1] = h1_; bl.q[0] = l0_; bl.q[1] = l1_;           \
        ah.u = AH; al.u = AL;                                                 \
        accH[nt] = __builtin_amdgcn_mfma_f32_16x16x32_f16(ah.h, bh.h, accH[nt], 0, 0, 0); \
        accX[nt] = __builtin_amdgcn_mfma_f32_16x16x32_f16(ah.h, bl.h, accX[nt], 0, 0, 0); \
        accX[nt] = __builtin_amdgcn_mfma_f32_16x16x32_f16(al.h, bh.h, accX[nt], 0, 0, 0); \
    } while (0)

    // stage g = csub*4 + nt; addr = trb + nt*2048 + csub*1024 (bytes)
#define COMPUTE(curhw)                                                        \
    do {                                                                      \
        const unsigned trb = lds0 + (unsigned)(curhw) * 2u + (unsigned)l * 8u;\
        u16x4 xh0, xh1, xl0, xl1, yh0, yh1, yl0, yl1;                         \
        __builtin_amdgcn_s_setprio(1);                                        \
        TRQ(xh0, xh1, xl0, xl1, trb);              /* g0 c0 nt0 */            \
        TRQ(yh0, yh1, yl0, yl1, trb + 2048u);      /* g1 c0 nt1 */            \
        WAIT4; MFMA3(0, dH0, dL0, xh0, xh1, xl0, xl1);                        \
        TRQ(xh0, xh1, xl0, xl1, trb + 4096u);      /* g2 c0 nt2 */            \
        WAIT4; MFMA3(1, dH0, dL0, yh0, yh1, yl0, yl1);                        \
        TRQ(yh0, yh1, yl0, yl1, trb + 6144u);      /* g3 c0 nt3 */            \
        WAIT4; MFMA3(2, dH0, dL0, xh0, xh1, xl0, xl1);                        \
        TRQ(xh0, xh1, xl0, xl1, trb + 1024u);      /* g4 c1 nt0 */            \
        WAIT4; MFMA3(3, dH0, dL0, yh0, yh1, yl0, yl1);                        \
        TRQ(yh0, yh1, yl0, yl1, trb + 3072u);      /* g5 c1 nt1 */            \
        WAIT4; MFMA3(0, dH1, dL1, xh0, xh1, xl0, xl1);                        \
        TRQ(xh0, xh1, xl0, xl1, trb + 5120u);      /* g6 c1 nt2 */            \
        WAIT4; MFMA3(1, dH1, dL1, yh0, yh1, yl0, yl1);                        \
        TRQ(yh0, yh1, yl0, yl1, trb + 7168u);      /* g7 c1 nt3 */            \
        WAIT4; MFMA3(2, dH1, dL1, xh0, xh1, xl0, xl1);                        \
        WAIT0; MFMA3(3, dH1, dL1, yh0, yh1, yl0, yl1);                        \
        __builtin_amdgcn_s_setprio(0);                                        \
    } while (0)

    // prologue: chunk0 -> A -> buf0; chunk1 -> B in flight; desc(0) in regs
    LOADFB(A, 0);
    LOADDESC(0);
    WRITEFB(A, 0);
    LOADFB(B, CCH);
    __syncthreads();

#pragma unroll 1
    for (int tp = 0; tp < 4; ++tp) {
        const int t0 = 2 * tp, t1 = 2 * tp + 1;
        if (t0 + 2 < 8) LOADFB(A, (t0 + 2) * CCH);
        COMPUTE(0);                            // chunk t0 (desc in regs)
        LOADDESC(t1 * CCH);                    // desc for t1 (regs now dead)
        WRITEFB(B, BUFHW);                     // chunk t0+1
        __syncthreads();
        if (t1 + 2 < 8) LOADFB(B, (t1 + 2) * CCH);
        COMPUTE(BUFHW);                        // chunk t1
        if (t1 + 1 < 8) { LOADDESC((t1 + 1) * CCH); WRITEFB(A, 0); }
        __syncthreads();
    }

    // ---- epilogue (buf0 dead: floats 0..4095 reused as scratch) ----
    float* fscr = (float*)&smem_us[0];
    *(float4*)&fscr[cr * 64 + o_ * 8]     = make_float4(sq[0], sq[1], sq[2], sq[3]);
    *(float4*)&fscr[cr * 64 + o_ * 8 + 4] = make_float4(sq[4], sq[5], sq[6], sq[7]);
    __syncthreads();
    if (tid < 64) {
        float s = 0.f;
#pragma unroll
        for (int g = 0; g < 32; ++g) s += fscr[g * 64 + tid];
        fscr[2048 + tid] = s;
    }
    __syncthreads();

    const float inv2048 = 1.f / 2048.f;
#pragma unroll
    for (int r = 0; r < 4; ++r) {
        float bv = 1e30f; int bn = 1 << 28;
#pragma unroll
        for (int nt = 0; nt < 4; ++nt) {       // nt ascending -> n ascending
            float cross = accH[nt][r] + accX[nt][r] * inv2048;
            float d = fscr[2048 + nt * 16 + (l & 15)] - 2.f * cross;
            int n = nb + nt * 16 + (l & 15);
            if (d < bv) { bv = d; bn = n; }
        }
#pragma unroll
        for (int m = 1; m < 16; m <<= 1) {     // reduce the 16 n-lanes
            float ov = __shfl_xor(bv, m);
            int   on = __shfl_xor(bn, m);
            if (ov < bv || (ov == bv && on < bn)) { bv = ov; bn = on; }
        }
        if ((l & 15) == 0) {
            int k = w * 16 + (l >> 4) * 4 + r;
            candV[(b * K_ + k) * NBLK + blockIdx.x] = bv;
            candN[(b * K_ + k) * NBLK + blockIdx.x] = bn;
        }
    }
#undef LOADFB
#undef LOADDESC
#undef CVT8
#undef WRITEFB
#undef TRQ
#undef WAIT4
#undef WAIT0
#undef MFMA3
#undef COMPUTE
}

// ---------------- kernel 4: cross-block argmin + offsets + mode ----------------
__global__ void k_redmode(const float* __restrict__ candV, const int* __restrict__ candN,
                          const int* __restrict__ rowA, const int* __restrict__ colA,
                          int* __restrict__ out) {
    __shared__ int r_s[64], c_s[64];
    int b = blockIdx.x, k = threadIdx.x;
    int base = (b * K_ + k) * NBLK;
    float bv = 1e30f; int bn = 1 << 28;
    for (int j = 0; j < NBLK; ++j) {
        float ov = candV[base + j]; int on = candN[base + j];
        if (ov < bv || (ov == bv && on < bn)) { bv = ov; bn = on; }
    }
    int rB = bn / W_, cB = bn - rB * W_;
    r_s[k] = rowA[b * K_ + k] - rB;
    c_s[k] = colA[b * K_ + k] - cB;
    __syncthreads();
    int mr = r_s[k], mc = c_s[k], cnt = 0;
#pragma unroll
    for (int j = 0; j < 64; ++j) cnt += (r_s[j] == mr && c_s[j] == mc) ? 1 : 0;
    int bk = k, bc = cnt;
    for (int m = 1; m < 64; m <<= 1) {
        int oc = __shfl_xor(bc, m);
        int ok = __shfl_xor(bk, m);
        if (oc > bc || (oc == bc && ok < bk)) { bc = oc; bk = ok; }
    }
    if (k == 0) { out[b * 2] = r_s[bk]; out[b * 2 + 1] = c_s[bk]; }
}

extern "C" void kernel_launch(void* const* d_in, const int* in_sizes, int n_in,
                              void* d_out, int out_size, void* d_ws, size_t ws_size,
                              hipStream_t stream) {
    const float* A  = (const float*)d_in[0];
    const float* FB = (const float*)d_in[1];
    char* ws = (char*)d_ws;
    float*     part  = (float*)(ws + OFF_PARTIAL);
    _Float16*  descH = (_Float16*)(ws + OFF_DESCH);
    _Float16*  descL = (_Float16*)(ws + OFF_DESCL);
    int*       rowA  = (int*)(ws + OFF_ROWA);
    int*       colA  = (int*)(ws + OFF_COLA);
    float*     candV = (float*)(ws + OFF_CANDV);
    int*       candN = (int*)(ws + OFF_CANDN);
    int*       out   = (int*)d_out;

    k_partial<<<dim3((B_ * HW) / 512, 8), 128, 0, stream>>>(A, part);
    k_selgather<<<dim3(K_, B_), 64, 0, stream>>>(part, A, rowA, colA, descH, descL);
    k_main<<<dim3(NBLK, B_), 256, 0, stream>>>(FB, descH, descL, candV, candN);
    k_redmode<<<dim3(B_), 64, 0, stream>>>(candV, candN, rowA, colA, out);
}

// Round 14
// 104.488 us; speedup vs baseline: 1.4265x; 1.4265x over previous
//
#include <hip/hip_runtime.h>
#include <hip/hip_bf16.h>
#include <math.h>

typedef _Float16 half8 __attribute__((ext_vector_type(8)));
typedef __fp16 fp16x2 __attribute__((ext_vector_type(2)));
typedef float f32x4 __attribute__((ext_vector_type(4)));
typedef unsigned short u16x4 __attribute__((ext_vector_type(4)));
typedef unsigned short u16x8 __attribute__((ext_vector_type(8)));

#define B_   8
#define C_   512
#define H_   96
#define W_   96
#define HW   9216
#define K_   64
#define PH   12
#define PW   12
#define NT   64     // n-tile per block in k_main
#define CCH  64     // c-chunk (8 chunks, 8 barriers)
#define NBLK 144    // n-blocks per batch (1152 blocks; target 4 blocks/CU)

// ws layout (bytes). candV/candN alias the dead `part` region.
#define OFF_PARTIAL 0u                    // float[8][73728]  -- dead after k_selgather
#define OFF_CANDV   0u                    // float[512*NBLK]
#define OFF_CANDN   294912u               // int[512*NBLK]
#define OFF_DESCH   2359296u              // _Float16[B*K*C]  ([b][k][c], hi)
#define OFF_DESCL   2883584u              // _Float16[B*K*C]  (lo * 2048)
#define OFF_ROWA    3407872u              // int[512]
#define OFF_COLA    3409920u              // int[512]

// k_main LDS (halfwords). One buffer = FBT only:
//   HI: [nt:4][csub:2][perm(cc):32][nn:16] = 4096 hw ; LO at +4096. BUFHW=8192.
#define FBT_LO 4096
#define BUFHW  8192

// ---------------- kernel 1: partial channel sums (float4) ----------------
__global__ __launch_bounds__(128) void k_partial(const float* __restrict__ A,
                                                 float* __restrict__ part) {
    int idx4 = blockIdx.x * 128 + threadIdx.x;
    int chunk = blockIdx.y;
    int b = idx4 / (HW / 4), hw4 = idx4 - b * (HW / 4);
    const float* p = A + ((size_t)(b * C_ + chunk * 64)) * HW + hw4 * 4;
    float4 s = make_float4(0.f, 0.f, 0.f, 0.f);
#pragma unroll
    for (int i = 0; i < 64; ++i) {
        float4 v = *(const float4*)&p[(size_t)i * HW];
        s.x += v.x; s.y += v.y; s.z += v.z; s.w += v.w;
    }
    *(float4*)&part[chunk * (B_ * HW) + b * HW + hw4 * 4] = s;
}

// ---------------- kernel 2: argmax select + split-f16 descriptor gather ----
__global__ void k_selgather(const float* __restrict__ part, const float* __restrict__ A,
                            int* __restrict__ rowA, int* __restrict__ colA,
                            _Float16* __restrict__ descH, _Float16* __restrict__ descL) {
    int k = blockIdx.x, b = blockIdx.y, lane = threadIdx.x;
    int gi = k >> 3, gj = k & 7;
    float bv = -1e30f; int bp = 1 << 20;
    for (int p = lane; p < PH * PW; p += 64) {
        int lr = p / PW, lc = p - lr * PW;
        int hw = (gi * PH + lr) * W_ + gj * PW + lc;
        float v = 0.f;
#pragma unroll
        for (int ch = 0; ch < 8; ++ch) v += part[ch * (B_ * HW) + b * HW + hw];
        if (v > bv || (v == bv && p < bp)) { bv = v; bp = p; }
    }
    for (int m = 1; m < 64; m <<= 1) {
        float ov = __shfl_xor(bv, m);
        int   op = __shfl_xor(bp, m);
        if (ov > bv || (ov == bv && op < bp)) { bv = ov; bp = op; }
    }
    int lr = bp / PW, lc = bp - lr * PW;
    int r = gi * PH + lr, c = gj * PW + lc;
    int flat = r * W_ + c;
    if (lane == 0) { rowA[b * K_ + k] = r; colA[b * K_ + k] = c; }
#pragma unroll
    for (int i = 0; i < 8; ++i) {
        int cc = i * 64 + lane;
        float v = A[((size_t)(b * C_ + cc)) * HW + flat];
        _Float16 h = (_Float16)v;
        _Float16 lo = (_Float16)((v - (float)h) * 2048.f);
        size_t o = ((size_t)(b * K_ + k)) * C_ + cc;
        descH[o] = h; descL[o] = lo;
    }
}

// ---------------- kernel 3: MFMA cross GEMM + fused argmin ----------------
// grid (144, 8), block 256 (4 waves). Wave w owns k-tile w*16..+15; 4 n-tiles
// of 16; K-chunks of 64 c (2 MFMA sub-chunks of 32). fp32-split f16 MFMA.
// fb: global->regs (single set, depth-1)->convert->tr-layout LDS (dbuf).
// desc (A-frags): DOUBLE-buffered register sets from global (L2-resident),
// issued one full compute phase before use.
__global__ __launch_bounds__(256, 3) void k_main(const float* __restrict__ FB,
                                                 const _Float16* __restrict__ descH,
                                                 const _Float16* __restrict__ descL,
                                                 float* __restrict__ candV,
                                                 int* __restrict__ candN) {
    __shared__ __attribute__((aligned(16))) unsigned short smem_us[2 * BUFHW];
    int b = blockIdx.y, nb = blockIdx.x * NT;
    int tid = threadIdx.x;
    int l = tid & 63;
    int w = tid >> 6;                          // wave id 0..3 (k-tile)
    const size_t baseB = (size_t)b * C_ * HW + nb;

    // fb staging map (all 256 threads): o = n-octet 0..7, cr = c-row 0..31
    const int o_ = tid & 7;
    const int cr = tid >> 3;
    const int nt_ = o_ >> 1, oct_ = o_ & 1;
    const int stb = nt_ * 1024 + ((cr >> 2) & 1) * 256 + (cr >> 3) * 64
                    + (cr & 3) * 16 + oct_ * 8;

    f32x4 accH[4], accX[4];
#pragma unroll
    for (int nt = 0; nt < 4; ++nt) {
        accH[nt] = (f32x4){0.f, 0.f, 0.f, 0.f};
        accX[nt] = (f32x4){0.f, 0.f, 0.f, 0.f};
    }
    float sq[8];
#pragma unroll
    for (int j = 0; j < 8; ++j) sq[j] = 0.f;

    // staging regs: FB single set; desc double set (A=even chunks, B=odd)
    float4 fa0, fa1, fb0, fb1;
    u16x8 AdH0, AdH1, AdL0, AdL1;
    u16x8 BdH0, BdH1, BdL0, BdL1;

#define LOADFB(c0)                                                            \
    do {                                                                      \
        const float* p0 = &FB[baseB + (size_t)((c0) + cr) * HW + o_ * 8];     \
        fa0 = *(const float4*)p0; fa1 = *(const float4*)(p0 + 4);             \
        const float* p1 = &FB[baseB + (size_t)((c0) + cr + 32) * HW + o_ * 8];\
        fb0 = *(const float4*)p1; fb1 = *(const float4*)(p1 + 4);             \
    } while (0)

#define LOADDESC(S, c0)                                                       \
    do {                                                                      \
        size_t o = ((size_t)(b * K_) + w * 16 + (l & 15)) * C_ + (c0) + (l >> 4) * 8; \
        S##dH0 = *(const u16x8*)&descH[o];                                    \
        S##dH1 = *(const u16x8*)&descH[o + 32];                               \
        S##dL0 = *(const u16x8*)&descL[o];                                    \
        S##dL1 = *(const u16x8*)&descL[o + 32];                               \
    } while (0)

#define CVT8(va, vb, hofs)                                                    \
    do {                                                                      \
        union { fp16x2 p[4]; half8 h; } hh, ll;                               \
        float vv[8] = {va.x, va.y, va.z, va.w, vb.x, vb.y, vb.z, vb.w};       \
        _Pragma("unroll")                                                     \
        for (int j = 0; j < 4; ++j) {                                         \
            float a = vv[2 * j], bq = vv[2 * j + 1];                          \
            fp16x2 hp = __builtin_amdgcn_cvt_pkrtz(a, bq);                    \
            float ha = (float)hp[0], hb = (float)hp[1];                       \
            fp16x2 lp = __builtin_amdgcn_cvt_pkrtz((a - ha) * 2048.f,         \
                                                   (bq - hb) * 2048.f);       \
            hh.p[j] = hp; ll.p[j] = lp;                                       \
            sq[2 * j]     = fmaf(a, a, sq[2 * j]);                            \
            sq[2 * j + 1] = fmaf(bq, bq, sq[2 * j + 1]);                      \
        }                                                                     \
        *(half8*)&smem_us[(hofs)] = hh.h;                                     \
        *(half8*)&smem_us[(hofs) + FBT_LO] = ll.h;                            \
    } while (0)

#define WRITEFB(bufhw)                                                        \
    do {                                                                      \
        CVT8(fa0, fa1, (bufhw) + stb);             /* csub 0 (c = cr)    */   \
        CVT8(fb0, fb1, (bufhw) + stb + 512);       /* csub 1 (c = cr+32) */   \
    } while (0)

    const unsigned lds0 = (unsigned)(size_t)&smem_us[0];

#define TRQ(d0, d1, d2, d3, addr)                                             \
    asm volatile("ds_read_b64_tr_b16 %0, %1"             : "=v"(d0) : "v"(addr)); \
    asm volatile("ds_read_b64_tr_b16 %0, %1 offset:512"  : "=v"(d1) : "v"(addr)); \
    asm volatile("ds_read_b64_tr_b16 %0, %1 offset:8192" : "=v"(d2) : "v"(addr)); \
    asm volatile("ds_read_b64_tr_b16 %0, %1 offset:8704" : "=v"(d3) : "v"(addr));

#define WAIT4 asm volatile("s_waitcnt lgkmcnt(4)" ::: "memory");              \
              __builtin_amdgcn_sched_barrier(0);
#define WAIT0 asm volatile("s_waitcnt lgkmcnt(0)" ::: "memory");              \
              __builtin_amdgcn_sched_barrier(0);

#define MFMA3(nt, AH, AL, h0_, h1_, l0_, l1_)                                 \
    do {                                                                      \
        union { u16x4 q[2]; half8 h; } bh, bl;                                \
        union { u16x8 u; half8 h; } ah, al;                                   \
        bh.q[0] = h0_; bh.q[1] = h1_; bl.q[0] = l0_; bl.q[1] = l1_;           \
        ah.u = AH; al.u = AL;                                                 \
        accH[nt] = __builtin_amdgcn_mfma_f32_16x16x32_f16(ah.h, bh.h, accH[nt], 0, 0, 0); \
        accX[nt] = __builtin_amdgcn_mfma_f32_16x16x32_f16(ah.h, bl.h, accX[nt], 0, 0, 0); \
        accX[nt] = __builtin_amdgcn_mfma_f32_16x16x32_f16(al.h, bh.h, accX[nt], 0, 0, 0); \
    } while (0)

#define COMPUTE(curhw, S)                                                     \
    do {                                                                      \
        const unsigned trb = lds0 + (unsigned)(curhw) * 2u + (unsigned)l * 8u;\
        u16x4 xh0, xh1, xl0, xl1, yh0, yh1, yl0, yl1;                         \
        __builtin_amdgcn_s_setprio(1);                                        \
        TRQ(xh0, xh1, xl0, xl1, trb);              /* c0 nt0 */               \
        TRQ(yh0, yh1, yl0, yl1, trb + 2048u);      /* c0 nt1 */               \
        WAIT4; MFMA3(0, S##dH0, S##dL0, xh0, xh1, xl0, xl1);                  \
        TRQ(xh0, xh1, xl0, xl1, trb + 4096u);      /* c0 nt2 */               \
        WAIT4; MFMA3(1, S##dH0, S##dL0, yh0, yh1, yl0, yl1);                  \
        TRQ(yh0, yh1, yl0, yl1, trb + 6144u);      /* c0 nt3 */               \
        WAIT4; MFMA3(2, S##dH0, S##dL0, xh0, xh1, xl0, xl1);                  \
        TRQ(xh0, xh1, xl0, xl1, trb + 1024u);      /* c1 nt0 */               \
        WAIT4; MFMA3(3, S##dH0, S##dL0, yh0, yh1, yl0, yl1);                  \
        TRQ(yh0, yh1, yl0, yl1, trb + 3072u);      /* c1 nt1 */               \
        WAIT4; MFMA3(0, S##dH1, S##dL1, xh0, xh1, xl0, xl1);                  \
        TRQ(xh0, xh1, xl0, xl1, trb + 5120u);      /* c1 nt2 */               \
        WAIT4; MFMA3(1, S##dH1, S##dL1, yh0, yh1, yl0, yl1);                  \
        TRQ(yh0, yh1, yl0, yl1, trb + 7168u);      /* c1 nt3 */               \
        WAIT4; MFMA3(2, S##dH1, S##dL1, xh0, xh1, xl0, xl1);                  \
        WAIT0; MFMA3(3, S##dH1, S##dL1, yh0, yh1, yl0, yl1);                  \
        __builtin_amdgcn_s_setprio(0);                                        \
    } while (0)

    // prologue: chunk0 -> buf0 (desc set A); chunk1 fb in regs
    LOADFB(0);
    LOADDESC(A, 0);
    WRITEFB(0);
    LOADFB(CCH);
    __syncthreads();

#pragma unroll 1
    for (int tp = 0; tp < 4; ++tp) {
        const int t0 = 2 * tp, t1 = 2 * tp + 1;
        // iter t0 (even chunk, buf0, desc A)
        LOADDESC(B, t1 * CCH);                 // desc for t1, a phase early
        COMPUTE(0, A);
        WRITEFB(BUFHW);                        // fb chunk t0+1
        if (t0 + 2 < 8) LOADFB((t0 + 2) * CCH);
        __syncthreads();
        // iter t1 (odd chunk, buf1, desc B)
        if (t1 + 1 < 8) LOADDESC(A, (t1 + 1) * CCH);
        COMPUTE(BUFHW, B);
        if (t1 + 1 < 8) WRITEFB(0);            // fb chunk t1+1
        if (t1 + 2 < 8) LOADFB((t1 + 2) * CCH);
        __syncthreads();
    }

    // ---- epilogue (buf0 dead: floats 0..4095 reused as scratch) ----
    float* fscr = (float*)&smem_us[0];
    *(float4*)&fscr[cr * 64 + o_ * 8]     = make_float4(sq[0], sq[1], sq[2], sq[3]);
    *(float4*)&fscr[cr * 64 + o_ * 8 + 4] = make_float4(sq[4], sq[5], sq[6], sq[7]);
    __syncthreads();
    if (tid < 64) {
        float s = 0.f;
#pragma unroll
        for (int g = 0; g < 32; ++g) s += fscr[g * 64 + tid];
        fscr[2048 + tid] = s;
    }
    __syncthreads();

    const float inv2048 = 1.f / 2048.f;
#pragma unroll
    for (int r = 0; r < 4; ++r) {
        float bv = 1e30f; int bn = 1 << 28;
#pragma unroll
        for (int nt = 0; nt < 4; ++nt) {       // nt ascending -> n ascending
            float cross = accH[nt][r] + accX[nt][r] * inv2048;
            float d = fscr[2048 + nt * 16 + (l & 15)] - 2.f * cross;
            int n = nb + nt * 16 + (l & 15);
            if (d < bv) { bv = d; bn = n; }
        }
#pragma unroll
        for (int m = 1; m < 16; m <<= 1) {     // reduce the 16 n-lanes
            float ov = __shfl_xor(bv, m);
            int   on = __shfl_xor(bn, m);
            if (ov < bv || (ov == bv && on < bn)) { bv = ov; bn = on; }
        }
        if ((l & 15) == 0) {
            int k = w * 16 + (l >> 4) * 4 + r;
            candV[(b * K_ + k) * NBLK + blockIdx.x] = bv;
            candN[(b * K_ + k) * NBLK + blockIdx.x] = bn;
        }
    }
#undef LOADFB
#undef LOADDESC
#undef CVT8
#undef WRITEFB
#undef TRQ
#undef WAIT4
#undef WAIT0
#undef MFMA3
#undef COMPUTE
}

// ---------------- kernel 4: cross-block argmin + offsets + mode ----------------
__global__ void k_redmode(const float* __restrict__ candV, const int* __restrict__ candN,
                          const int* __restrict__ rowA, const int* __restrict__ colA,
                          int* __restrict__ out) {
    __shared__ int r_s[64], c_s[64];
    int b = blockIdx.x, k = threadIdx.x;
    int base = (b * K_ + k) * NBLK;
    float bv = 1e30f; int bn = 1 << 28;
    for (int j = 0; j < NBLK; ++j) {
        float ov = candV[base + j]; int on = candN[base + j];
        if (ov < bv || (ov == bv && on < bn)) { bv = ov; bn = on; }
    }
    int rB = bn / W_, cB = bn - rB * W_;
    r_s[k] = rowA[b * K_ + k] - rB;
    c_s[k] = colA[b * K_ + k] - cB;
    __syncthreads();
    int mr = r_s[k], mc = c_s[k], cnt = 0;
#pragma unroll
    for (int j = 0; j < 64; ++j) cnt += (r_s[j] == mr && c_s[j] == mc) ? 1 : 0;
    int bk = k, bc = cnt;
    for (int m = 1; m < 64; m <<= 1) {
        int oc = __shfl_xor(bc, m);
        int ok = __shfl_xor(bk, m);
        if (oc > bc || (oc == bc && ok < bk)) { bc = oc; bk = ok; }
    }
    if (k == 0) { out[b * 2] = r_s[bk]; out[b * 2 + 1] = c_s[bk]; }
}

extern "C" void kernel_launch(void* const* d_in, const int* in_sizes, int n_in,
                              void* d_out, int out_size, void* d_ws, size_t ws_size,
                              hipStream_t stream) {
    const float* A  = (const float*)d_in[0];
    const float* FB = (const float*)d_in[1];
    char* ws = (char*)d_ws;
    float*     part  = (float*)(ws + OFF_PARTIAL);
    _Float16*  descH = (_Float16*)(ws + OFF_DESCH);
    _Float16*  descL = (_Float16*)(ws + OFF_DESCL);
    int*       rowA  = (int*)(ws + OFF_ROWA);
    int*       colA  = (int*)(ws + OFF_COLA);
    float*     candV = (float*)(ws + OFF_CANDV);
    int*       candN = (int*)(ws + OFF_CANDN);
    int*       out   = (int*)d_out;

    k_partial<<<dim3((B_ * HW) / 512, 8), 128, 0, stream>>>(A, part);
    k_selgather<<<dim3(K_, B_), 64, 0, stream>>>(part, A, rowA, colA, descH, descL);
    k_main<<<dim3(NBLK, B_), 256, 0, stream>>>(FB, descH, descL, candV, candN);
    k_redmode<<<dim3(B_), 64, 0, stream>>>(candV, candN, rowA, colA, out);
}

// Round 15
// 82.771 us; speedup vs baseline: 1.8008x; 1.2624x over previous
//
#include <hip/hip_runtime.h>
#include <hip/hip_bf16.h>
#include <math.h>

typedef _Float16 half8 __attribute__((ext_vector_type(8)));
typedef __fp16 fp16x2 __attribute__((ext_vector_type(2)));
typedef float f32x4 __attribute__((ext_vector_type(4)));
typedef unsigned short u16x4 __attribute__((ext_vector_type(4)));
typedef unsigned short u16x8 __attribute__((ext_vector_type(8)));
typedef unsigned long long u64;

#define B_   8
#define C_   512
#define H_   96
#define W_   96
#define HW   9216
#define K_   64
#define PH   12
#define PW   12
#define NT   96     // n-tile per block in k_main
#define CCH  32     // c-chunk
#define NBLK 96     // n-blocks per batch (768 blocks = 3/CU exact)

// ws layout (bytes).
#define OFF_PARTIAL 0u                    // float[8][73728]  -- dead after k_selgather
#define OFF_DESCH   2359296u              // _Float16[B*K*C]  ([b][k][c], hi)
#define OFF_DESCL   2883584u              // _Float16[B*K*C]  (lo * 2048)
#define OFF_ROWA    3407872u              // int[512]
#define OFF_COLA    3409920u              // int[512]
#define OFF_SLOTS   3411968u              // u64[512] packed (key|n) argmin slots

// k_main LDS halfword offsets within one buffer:
#define FBT_HI 0
#define FBT_LO 3072
#define DSC_HI 6144
#define DSC_LO 8704
#define BUFHW  11264

// ---------------- kernel 1: partial channel sums (float4) + slot init ------
__global__ __launch_bounds__(256) void k_partial(const float* __restrict__ A,
                                                 float* __restrict__ part,
                                                 u64* __restrict__ slots) {
    if (blockIdx.x == 0 && blockIdx.y == 0) {   // init argmin slots (512 u64)
        slots[threadIdx.x] = ~0ull;
        slots[threadIdx.x + 256] = ~0ull;
    }
    int bxs = (blockIdx.x & 7) * 9 + (blockIdx.x >> 3);   // XCD-chunked swizzle (72=8*9)
    int idx4 = bxs * 256 + threadIdx.x;
    int chunk = blockIdx.y;
    int b = idx4 / (HW / 4), hw4 = idx4 - b * (HW / 4);
    const float* p = A + ((size_t)(b * C_ + chunk * 64)) * HW + hw4 * 4;
    float4 s = make_float4(0.f, 0.f, 0.f, 0.f);
#pragma unroll
    for (int i = 0; i < 64; ++i) {
        float4 v = *(const float4*)&p[(size_t)i * HW];
        s.x += v.x; s.y += v.y; s.z += v.z; s.w += v.w;
    }
    *(float4*)&part[chunk * (B_ * HW) + b * HW + hw4 * 4] = s;
}

// ---------------- kernel 2: argmax select + split-f16 descriptor gather ----
__global__ void k_selgather(const float* __restrict__ part, const float* __restrict__ A,
                            int* __restrict__ rowA, int* __restrict__ colA,
                            _Float16* __restrict__ descH, _Float16* __restrict__ descL) {
    int k = blockIdx.x, b = blockIdx.y, lane = threadIdx.x;
    int gi = k >> 3, gj = k & 7;
    float bv = -1e30f; int bp = 1 << 20;
    for (int p = lane; p < PH * PW; p += 64) {
        int lr = p / PW, lc = p - lr * PW;
        int hw = (gi * PH + lr) * W_ + gj * PW + lc;
        float v = 0.f;
#pragma unroll
        for (int ch = 0; ch < 8; ++ch) v += part[ch * (B_ * HW) + b * HW + hw];
        if (v > bv || (v == bv && p < bp)) { bv = v; bp = p; }
    }
    for (int m = 1; m < 64; m <<= 1) {
        float ov = __shfl_xor(bv, m);
        int   op = __shfl_xor(bp, m);
        if (ov > bv || (ov == bv && op < bp)) { bv = ov; bp = op; }
    }
    int lr = bp / PW, lc = bp - lr * PW;
    int r = gi * PH + lr, c = gj * PW + lc;
    int flat = r * W_ + c;
    if (lane == 0) { rowA[b * K_ + k] = r; colA[b * K_ + k] = c; }
#pragma unroll
    for (int i = 0; i < 8; ++i) {
        int cc = i * 64 + lane;
        float v = A[((size_t)(b * C_ + cc)) * HW + flat];
        _Float16 h = (_Float16)v;
        _Float16 lo = (_Float16)((v - (float)h) * 2048.f);
        size_t o = ((size_t)(b * K_ + k)) * C_ + cc;
        descH[o] = h; descL[o] = lo;
    }
}

// ---------------- kernel 3: MFMA cross GEMM + fused argmin ----------------
// R12 structure (proven 93.3): grid (96,8), 256 thr (4 waves), NT=96, CCH=32,
// depth-2 A/B reg prefetch, 3-deep tr-read pipeline. Changes: XCD swizzle on
// blockIdx.x; epilogue -> packed-u64 atomicMin (deterministic, exact ties).
__global__ __launch_bounds__(256, 3) void k_main(const float* __restrict__ FB,
                                                 const _Float16* __restrict__ descH,
                                                 const _Float16* __restrict__ descL,
                                                 u64* __restrict__ slots) {
    __shared__ __attribute__((aligned(16))) unsigned short smem_us[2 * BUFHW];
    int b = blockIdx.y;
    int bxs = (blockIdx.x & 7) * 12 + (blockIdx.x >> 3);  // 96 = 8*12, bijective
    int nb = bxs * NT;
    int tid = threadIdx.x;
    int l = tid & 63;
    int w = tid >> 6;                          // wave id 0..3 (M-tile)
    const size_t baseB = (size_t)b * C_ * HW + nb;

    const int so = tid % 12;
    const int scb = tid / 12;
    const int st_nt = so >> 1, st_nn0 = (so & 1) * 8;
    const int dk = tid >> 2, dco = tid & 3;

    f32x4 accH[6], accX[6];
#pragma unroll
    for (int nt = 0; nt < 6; ++nt) {
        accH[nt] = (f32x4){0.f, 0.f, 0.f, 0.f};
        accX[nt] = (f32x4){0.f, 0.f, 0.f, 0.f};
    }
    float sq[8];
#pragma unroll
    for (int j = 0; j < 8; ++j) sq[j] = 0.f;

    float4 Ar0a, Ar0b, Ar1a, Ar1b; u16x8 ArdH, ArdL;
    float4 Br0a, Br0b, Br1a, Br1b; u16x8 BrdH, BrdL;

#define LOADALL(S, c0)                                                        \
    do {                                                                      \
        if (tid < 192) {                                                      \
            const float* p0 = &FB[baseB + (size_t)((c0) + scb) * HW + so * 8];      \
            const float* p1 = &FB[baseB + (size_t)((c0) + scb + 16) * HW + so * 8]; \
            S##r0a = *(const float4*)p0; S##r0b = *(const float4*)(p0 + 4);   \
            S##r1a = *(const float4*)p1; S##r1b = *(const float4*)(p1 + 4);   \
        }                                                                     \
        size_t o = ((size_t)(b * K_) + dk) * C_ + (c0) + dco * 8;             \
        S##rdH = *(const u16x8*)&descH[o];                                    \
        S##rdL = *(const u16x8*)&descL[o];                                    \
    } while (0)

#define CVT8(va, vb, hofs)                                                    \
    do {                                                                      \
        union { fp16x2 p[4]; half8 h; } hh, ll;                               \
        float vv[8] = {va.x, va.y, va.z, va.w, vb.x, vb.y, vb.z, vb.w};       \
        _Pragma("unroll")                                                     \
        for (int j = 0; j < 4; ++j) {                                         \
            float a = vv[2 * j], bq = vv[2 * j + 1];                          \
            fp16x2 hp = __builtin_amdgcn_cvt_pkrtz(a, bq);                    \
            float ha = (float)hp[0], hb = (float)hp[1];                       \
            fp16x2 lp = __builtin_amdgcn_cvt_pkrtz((a - ha) * 2048.f,         \
                                                   (bq - hb) * 2048.f);       \
            hh.p[j] = hp; ll.p[j] = lp;                                       \
            sq[2 * j]     = fmaf(a, a, sq[2 * j]);                            \
            sq[2 * j + 1] = fmaf(bq, bq, sq[2 * j + 1]);                      \
        }                                                                     \
        *(half8*)&smem_us[(hofs)] = hh.h;                                     \
        *(half8*)&smem_us[(hofs) + FBT_LO] = ll.h;                            \
    } while (0)

#define WRITEALL(S, bufhw)                                                    \
    do {                                                                      \
        if (tid < 192) {                                                      \
            int c = scb;                                                      \
            int off0 = (bufhw) + FBT_HI + st_nt * 512 + ((c >> 2) & 1) * 256  \
                       + (c >> 3) * 64 + (c & 3) * 16 + st_nn0;               \
            CVT8(S##r0a, S##r0b, off0);                                       \
            c = scb + 16;                                                     \
            int off1 = (bufhw) + FBT_HI + st_nt * 512 + ((c >> 2) & 1) * 256  \
                       + (c >> 3) * 64 + (c & 3) * 16 + st_nn0;               \
            CVT8(S##r1a, S##r1b, off1);                                       \
        }                                                                     \
        *(u16x8*)&smem_us[(bufhw) + DSC_HI + dk * 40 + dco * 8] = S##rdH;     \
        *(u16x8*)&smem_us[(bufhw) + DSC_LO + dk * 40 + dco * 8] = S##rdL;     \
    } while (0)

    const unsigned lds0 = (unsigned)(size_t)&smem_us[0];

#define TRQ(d0, d1, d2, d3, addr)                                             \
    asm volatile("ds_read_b64_tr_b16 %0, %1"             : "=v"(d0) : "v"(addr)); \
    asm volatile("ds_read_b64_tr_b16 %0, %1 offset:512"  : "=v"(d1) : "v"(addr)); \
    asm volatile("ds_read_b64_tr_b16 %0, %1 offset:6144" : "=v"(d2) : "v"(addr)); \
    asm volatile("ds_read_b64_tr_b16 %0, %1 offset:6656" : "=v"(d3) : "v"(addr));

#define WAIT8 asm volatile("s_waitcnt lgkmcnt(8)" ::: "memory");              \
              __builtin_amdgcn_sched_barrier(0);
#define WAIT4 asm volatile("s_waitcnt lgkmcnt(4)" ::: "memory");              \
              __builtin_amdgcn_sched_barrier(0);
#define WAIT0 asm volatile("s_waitcnt lgkmcnt(0)" ::: "memory");              \
              __builtin_amdgcn_sched_barrier(0);

#define MFMA3(nt, h0_, h1_, l0_, l1_)                                         \
    do {                                                                      \
        union { u16x4 q[2]; half8 h; } bh, bl;                                \
        bh.q[0] = h0_; bh.q[1] = h1_; bl.q[0] = l0_; bl.q[1] = l1_;           \
        accH[nt] = __builtin_amdgcn_mfma_f32_16x16x32_f16(aHu.h, bh.h, accH[nt], 0, 0, 0); \
        accX[nt] = __builtin_amdgcn_mfma_f32_16x16x32_f16(aHu.h, bl.h, accX[nt], 0, 0, 0); \
        accX[nt] = __builtin_amdgcn_mfma_f32_16x16x32_f16(aLu.h, bh.h, accX[nt], 0, 0, 0); \
    } while (0)

#define COMPUTE(cur)                                                          \
    do {                                                                      \
        union { u16x8 u; half8 h; } aHu, aLu;                                 \
        const unsigned abase = lds0 +                                         \
            (unsigned)((cur) + DSC_HI + (w * 16 + (l & 15)) * 40 + (l >> 4) * 8) * 2u; \
        __builtin_amdgcn_s_setprio(1);                                        \
        asm volatile("ds_read_b128 %0, %1"             : "=v"(aHu.u) : "v"(abase)); \
        asm volatile("ds_read_b128 %0, %1 offset:5120" : "=v"(aLu.u) : "v"(abase)); \
        const unsigned trb = lds0 + (unsigned)(cur) * 2u + (unsigned)l * 8u;  \
        u16x4 xh0, xh1, xl0, xl1, yh0, yh1, yl0, yl1, zh0, zh1, zl0, zl1;     \
        TRQ(xh0, xh1, xl0, xl1, trb);                                         \
        TRQ(yh0, yh1, yl0, yl1, trb + 1024u);                                 \
        TRQ(zh0, zh1, zl0, zl1, trb + 2048u);                                 \
        WAIT8;                                                                \
        MFMA3(0, xh0, xh1, xl0, xl1);                                         \
        TRQ(xh0, xh1, xl0, xl1, trb + 3072u);                                 \
        WAIT8;                                                                \
        MFMA3(1, yh0, yh1, yl0, yl1);                                         \
        TRQ(yh0, yh1, yl0, yl1, trb + 4096u);                                 \
        WAIT8;                                                                \
        MFMA3(2, zh0, zh1, zl0, zl1);                                         \
        TRQ(zh0, zh1, zl0, zl1, trb + 5120u);                                 \
        WAIT8;                                                                \
        MFMA3(3, xh0, xh1, xl0, xl1);                                         \
        WAIT4;                                                                \
        MFMA3(4, yh0, yh1, yl0, yl1);                                         \
        WAIT0;                                                                \
        MFMA3(5, zh0, zh1, zl0, zl1);                                         \
        __builtin_amdgcn_s_setprio(0);                                        \
    } while (0)

    LOADALL(A, 0);
    WRITEALL(A, 0);
    LOADALL(B, CCH);
    __syncthreads();

#pragma unroll 1
    for (int tp = 0; tp < 8; ++tp) {
        const int t0 = 2 * tp, t1 = 2 * tp + 1;
        if (t0 + 2 < 16) LOADALL(A, (t0 + 2) * CCH);
        COMPUTE(0);
        if (t0 + 1 < 16) WRITEALL(B, BUFHW);
        __syncthreads();
        if (t1 + 2 < 16) LOADALL(B, (t1 + 2) * CCH);
        COMPUTE(BUFHW);
        if (t1 + 1 < 16) WRITEALL(A, 0);
        __syncthreads();
    }

    // ---- epilogue (buf0 dead: floats 0..1631 reused as scratch) ----
    float* fscr = (float*)&smem_us[0];
    if (tid < 192) {
        *(float4*)&fscr[scb * 96 + so * 8]     = make_float4(sq[0], sq[1], sq[2], sq[3]);
        *(float4*)&fscr[scb * 96 + so * 8 + 4] = make_float4(sq[4], sq[5], sq[6], sq[7]);
    }
    __syncthreads();
    if (tid < 96) {
        float s = 0.f;
#pragma unroll
        for (int g = 0; g < 16; ++g) s += fscr[g * 96 + tid];
        fscr[1536 + tid] = s;
    }
    __syncthreads();

    const float inv2048 = 1.f / 2048.f;
#pragma unroll
    for (int r = 0; r < 4; ++r) {
        float bv = 1e30f; int bn = 1 << 28;
#pragma unroll
        for (int nt = 0; nt < 6; ++nt) {       // nt ascending -> n ascending
            float cross = accH[nt][r] + accX[nt][r] * inv2048;
            float d = fscr[1536 + nt * 16 + (l & 15)] - 2.f * cross;
            int n = nb + nt * 16 + (l & 15);
            if (d < bv) { bv = d; bn = n; }
        }
#pragma unroll
        for (int m = 1; m < 16; m <<= 1) {     // reduce the 16 n-lanes
            float ov = __shfl_xor(bv, m);
            int   on = __shfl_xor(bn, m);
            if (ov < bv || (ov == bv && on < bn)) { bv = ov; bn = on; }
        }
        if ((l & 15) == 0) {
            int k = w * 16 + (l >> 4) * 4 + r;
            unsigned bits = __float_as_uint(bv);
            unsigned key = (bits & 0x80000000u) ? ~bits : (bits | 0x80000000u);
            u64 packed = ((u64)key << 32) | (unsigned)bn;
            atomicMin(&slots[b * K_ + k], packed);   // order-independent, exact ties
        }
    }
#undef LOADALL
#undef CVT8
#undef WRITEALL
#undef TRQ
#undef WAIT8
#undef WAIT4
#undef WAIT0
#undef MFMA3
#undef COMPUTE
}

// ---------------- kernel 4: decode slots + offsets + mode ----------------
__global__ void k_redmode(const u64* __restrict__ slots,
                          const int* __restrict__ rowA, const int* __restrict__ colA,
                          int* __restrict__ out) {
    __shared__ int r_s[64], c_s[64];
    int b = blockIdx.x, k = threadIdx.x;
    u64 s = slots[b * K_ + k];
    int bn = (int)(unsigned)(s & 0xFFFFFFFFull);
    int rB = bn / W_, cB = bn - rB * W_;
    r_s[k] = rowA[b * K_ + k] - rB;
    c_s[k] = colA[b * K_ + k] - cB;
    __syncthreads();
    int mr = r_s[k], mc = c_s[k], cnt = 0;
#pragma unroll
    for (int j = 0; j < 64; ++j) cnt += (r_s[j] == mr && c_s[j] == mc) ? 1 : 0;
    int bk = k, bc = cnt;
    for (int m = 1; m < 64; m <<= 1) {
        int oc = __shfl_xor(bc, m);
        int ok = __shfl_xor(bk, m);
        if (oc > bc || (oc == bc && ok < bk)) { bc = oc; bk = ok; }
    }
    if (k == 0) { out[b * 2] = r_s[bk]; out[b * 2 + 1] = c_s[bk]; }
}

extern "C" void kernel_launch(void* const* d_in, const int* in_sizes, int n_in,
                              void* d_out, int out_size, void* d_ws, size_t ws_size,
                              hipStream_t stream) {
    const float* A  = (const float*)d_in[0];
    const float* FB = (const float*)d_in[1];
    char* ws = (char*)d_ws;
    float*     part  = (float*)(ws + OFF_PARTIAL);
    _Float16*  descH = (_Float16*)(ws + OFF_DESCH);
    _Float16*  descL = (_Float16*)(ws + OFF_DESCL);
    int*       rowA  = (int*)(ws + OFF_ROWA);
    int*       colA  = (int*)(ws + OFF_COLA);
    u64*       slots = (u64*)(ws + OFF_SLOTS);
    int*       out   = (int*)d_out;

    k_partial<<<dim3((B_ * HW) / 1024, 8), 256, 0, stream>>>(A, part, slots);
    k_selgather<<<dim3(K_, B_), 64, 0, stream>>>(part, A, rowA, colA, descH, descL);
    k_main<<<dim3(NBLK, B_), 256, 0, stream>>>(FB, descH, descL, slots);
    k_redmode<<<dim3(B_), 64, 0, stream>>>(slots, rowA, colA, out);
}

// Round 17
// 81.756 us; speedup vs baseline: 1.8231x; 1.0124x over previous
//
#include <hip/hip_runtime.h>
#include <hip/hip_bf16.h>
#include <math.h>

typedef _Float16 half8 __attribute__((ext_vector_type(8)));
typedef __fp16 fp16x2 __attribute__((ext_vector_type(2)));
typedef float f32x4 __attribute__((ext_vector_type(4)));
typedef unsigned short u16x4 __attribute__((ext_vector_type(4)));
typedef unsigned short u16x8 __attribute__((ext_vector_type(8)));
typedef unsigned long long u64;

#define B_   8
#define C_   512
#define H_   96
#define W_   96
#define HW   9216
#define K_   64
#define PH   12
#define PW   12
#define NT   96     // n-tile per block in k_main
#define CCH  32     // c-chunk
#define NBLK 96     // n-blocks per batch (768 blocks)

// ws layout (bytes).
#define OFF_PARTIAL 0u                    // float[8][73728]  -- dead after k_selgather
#define OFF_DESCH   2359296u              // _Float16[B*K*C]  ([b][k][c], hi)
#define OFF_DESCL   2883584u              // _Float16[B*K*C]  (lo * 2048)
#define OFF_ROWA    3407872u              // int[512]
#define OFF_COLA    3409920u              // int[512]
#define OFF_SLOTS   3411968u              // u64[512] packed (key|n) argmin slots

// k_main LDS (halfwords). FBT only: HI [nt:6][perm_c:32][nn:16] = 3072 hw,
// LO at +3072. BUFHW = 6144 hw = 12 KB/buffer; 2 buffers = 24 KB.
#define FBT_LO 3072
#define BUFHW  6144

// ---------------- kernel 1: partial channel sums (float4) + slot init ------
__global__ __launch_bounds__(256) void k_partial(const float* __restrict__ A,
                                                 float* __restrict__ part,
                                                 u64* __restrict__ slots) {
    if (blockIdx.x == 0 && blockIdx.y == 0) {   // init argmin slots (512 u64)
        slots[threadIdx.x] = ~0ull;
        slots[threadIdx.x + 256] = ~0ull;
    }
    int bxs = (blockIdx.x & 7) * 9 + (blockIdx.x >> 3);   // XCD swizzle (72=8*9)
    int idx4 = bxs * 256 + threadIdx.x;
    int chunk = blockIdx.y;
    int b = idx4 / (HW / 4), hw4 = idx4 - b * (HW / 4);
    const float* p = A + ((size_t)(b * C_ + chunk * 64)) * HW + hw4 * 4;
    float4 s = make_float4(0.f, 0.f, 0.f, 0.f);
#pragma unroll
    for (int i = 0; i < 64; ++i) {
        float4 v = *(const float4*)&p[(size_t)i * HW];
        s.x += v.x; s.y += v.y; s.z += v.z; s.w += v.w;
    }
    *(float4*)&part[chunk * (B_ * HW) + b * HW + hw4 * 4] = s;
}

// ---------------- kernel 2: argmax select + split-f16 descriptor gather ----
__global__ void k_selgather(const float* __restrict__ part, const float* __restrict__ A,
                            int* __restrict__ rowA, int* __restrict__ colA,
                            _Float16* __restrict__ descH, _Float16* __restrict__ descL) {
    int k = blockIdx.x, b = blockIdx.y, lane = threadIdx.x;
    int gi = k >> 3, gj = k & 7;
    float bv = -1e30f; int bp = 1 << 20;
    for (int p = lane; p < PH * PW; p += 64) {
        int lr = p / PW, lc = p - lr * PW;
        int hw = (gi * PH + lr) * W_ + gj * PW + lc;
        float v = 0.f;
#pragma unroll
        for (int ch = 0; ch < 8; ++ch) v += part[ch * (B_ * HW) + b * HW + hw];
        if (v > bv || (v == bv && p < bp)) { bv = v; bp = p; }
    }
    for (int m = 1; m < 64; m <<= 1) {
        float ov = __shfl_xor(bv, m);
        int   op = __shfl_xor(bp, m);
        if (ov > bv || (ov == bv && op < bp)) { bv = ov; bp = op; }
    }
    int lr = bp / PW, lc = bp - lr * PW;
    int r = gi * PH + lr, c = gj * PW + lc;
    int flat = r * W_ + c;
    if (lane == 0) { rowA[b * K_ + k] = r; colA[b * K_ + k] = c; }
#pragma unroll
    for (int i = 0; i < 8; ++i) {
        int cc = i * 64 + lane;
        float v = A[((size_t)(b * C_ + cc)) * HW + flat];
        _Float16 h = (_Float16)v;
        _Float16 lo = (_Float16)((v - (float)h) * 2048.f);
        size_t o = ((size_t)(b * K_ + k)) * C_ + cc;
        descH[o] = h; descL[o] = lo;
    }
}

// ---------------- kernel 3: MFMA cross GEMM + fused argmin ----------------
// R15 structure with DSC moved out of LDS: each wave's A-frags are loaded
// straight from global (desc 1MB, L2-hot) into DOUBLE-buffered register
// sets, issued 2 phases before use. LDS = FBT only (24 KB) -> 4+ blocks/CU.
// FB staging: single register set, depth-1 (depth-2 measured neutral).
__global__ __launch_bounds__(256, 3) void k_main(const float* __restrict__ FB,
                                                 const _Float16* __restrict__ descH,
                                                 const _Float16* __restrict__ descL,
                                                 u64* __restrict__ slots) {
    __shared__ __attribute__((aligned(16))) unsigned short smem_us[2 * BUFHW];
    int b = blockIdx.y;
    int bxs = (blockIdx.x & 7) * 12 + (blockIdx.x >> 3);  // 96 = 8*12, bijective
    int nb = bxs * NT;
    int tid = threadIdx.x;
    int l = tid & 63;
    int w = tid >> 6;                          // wave id 0..3 (M-tile)
    const size_t baseB = (size_t)b * C_ * HW + nb;

    const int so = tid % 12;
    const int scb = tid / 12;
    const int st_nt = so >> 1, st_nn0 = (so & 1) * 8;
    // per-lane desc source row/octet (wave w covers k rows w*16..w*16+15)
    const size_t dbase = ((size_t)(b * K_) + w * 16 + (l & 15)) * C_ + (l >> 4) * 8;

    f32x4 accH[6], accX[6];
#pragma unroll
    for (int nt = 0; nt < 6; ++nt) {
        accH[nt] = (f32x4){0.f, 0.f, 0.f, 0.f};
        accX[nt] = (f32x4){0.f, 0.f, 0.f, 0.f};
    }
    float sq[8];
#pragma unroll
    for (int j = 0; j < 8; ++j) sq[j] = 0.f;

    float4 r0a, r0b, r1a, r1b;                 // FB staging (single set)
    u16x8 AdH, AdL, BdH, BdL;                  // desc double-buffered sets

#define LOADFB(c0)                                                            \
    do {                                                                      \
        if (tid < 192) {                                                      \
            const float* p0 = &FB[baseB + (size_t)((c0) + scb) * HW + so * 8];      \
            const float* p1 = &FB[baseB + (size_t)((c0) + scb + 16) * HW + so * 8]; \
            r0a = *(const float4*)p0; r0b = *(const float4*)(p0 + 4);         \
            r1a = *(const float4*)p1; r1b = *(const float4*)(p1 + 4);         \
        }                                                                     \
    } while (0)

#define LOADDESC(S, c0)                                                       \
    do {                                                                      \
        S##dH = *(const u16x8*)&descH[dbase + (c0)];                          \
        S##dL = *(const u16x8*)&descL[dbase + (c0)];                          \
    } while (0)

#define CVT8(va, vb, hofs)                                                    \
    do {                                                                      \
        union { fp16x2 p[4]; half8 h; } hh, ll;                               \
        float vv[8] = {va.x, va.y, va.z, va.w, vb.x, vb.y, vb.z, vb.w};       \
        _Pragma("unroll")                                                     \
        for (int j = 0; j < 4; ++j) {                                         \
            float a = vv[2 * j], bq = vv[2 * j + 1];                          \
            fp16x2 hp = __builtin_amdgcn_cvt_pkrtz(a, bq);                    \
            float ha = (float)hp[0], hb = (float)hp[1];                       \
            fp16x2 lp = __builtin_amdgcn_cvt_pkrtz((a - ha) * 2048.f,         \
                                                   (bq - hb) * 2048.f);       \
            hh.p[j] = hp; ll.p[j] = lp;                                       \
            sq[2 * j]     = fmaf(a, a, sq[2 * j]);                            \
            sq[2 * j + 1] = fmaf(bq, bq, sq[2 * j + 1]);                      \
        }                                                                     \
        *(half8*)&smem_us[(hofs)] = hh.h;                                     \
        *(half8*)&smem_us[(hofs) + FBT_LO] = ll.h;                            \
    } while (0)

#define WRITEFB(bufhw)                                                        \
    do {                                                                      \
        if (tid < 192) {                                                      \
            int c = scb;                                                      \
            int off0 = (bufhw) + st_nt * 512 + ((c >> 2) & 1) * 256           \
                       + (c >> 3) * 64 + (c & 3) * 16 + st_nn0;               \
            CVT8(r0a, r0b, off0);                                             \
            c = scb + 16;                                                     \
            int off1 = (bufhw) + st_nt * 512 + ((c >> 2) & 1) * 256           \
                       + (c >> 3) * 64 + (c & 3) * 16 + st_nn0;               \
            CVT8(r1a, r1b, off1);                                             \
        }                                                                     \
    } while (0)

    const unsigned lds0 = (unsigned)(size_t)&smem_us[0];

#define TRQ(d0, d1, d2, d3, addr)                                             \
    asm volatile("ds_read_b64_tr_b16 %0, %1"             : "=v"(d0) : "v"(addr)); \
    asm volatile("ds_read_b64_tr_b16 %0, %1 offset:512"  : "=v"(d1) : "v"(addr)); \
    asm volatile("ds_read_b64_tr_b16 %0, %1 offset:6144" : "=v"(d2) : "v"(addr)); \
    asm volatile("ds_read_b64_tr_b16 %0, %1 offset:6656" : "=v"(d3) : "v"(addr));

#define WAIT8 asm volatile("s_waitcnt lgkmcnt(8)" ::: "memory");              \
              __builtin_amdgcn_sched_barrier(0);
#define WAIT4 asm volatile("s_waitcnt lgkmcnt(4)" ::: "memory");              \
              __builtin_amdgcn_sched_barrier(0);
#define WAIT0 asm volatile("s_waitcnt lgkmcnt(0)" ::: "memory");              \
              __builtin_amdgcn_sched_barrier(0);

#define MFMA3(nt, h0_, h1_, l0_, l1_)                                         \
    do {                                                                      \
        union { u16x4 q[2]; half8 h; } bh, bl;                                \
        bh.q[0] = h0_; bh.q[1] = h1_; bl.q[0] = l0_; bl.q[1] = l1_;           \
        accH[nt] = __builtin_amdgcn_mfma_f32_16x16x32_f16(aHu.h, bh.h, accH[nt], 0, 0, 0); \
        accX[nt] = __builtin_amdgcn_mfma_f32_16x16x32_f16(aHu.h, bl.h, accX[nt], 0, 0, 0); \
        accX[nt] = __builtin_amdgcn_mfma_f32_16x16x32_f16(aLu.h, bh.h, accX[nt], 0, 0, 0); \
    } while (0)

#define COMPUTE(cur, S)                                                       \
    do {                                                                      \
        union { u16x8 u; half8 h; } aHu, aLu;                                 \
        aHu.u = S##dH; aLu.u = S##dL;                                         \
        __builtin_amdgcn_s_setprio(1);                                        \
        const unsigned trb = lds0 + (unsigned)(cur) * 2u + (unsigned)l * 8u;  \
        u16x4 xh0, xh1, xl0, xl1, yh0, yh1, yl0, yl1, zh0, zh1, zl0, zl1;     \
        TRQ(xh0, xh1, xl0, xl1, trb);                                         \
        TRQ(yh0, yh1, yl0, yl1, trb + 1024u);                                 \
        TRQ(zh0, zh1, zl0, zl1, trb + 2048u);                                 \
        WAIT8;                                                                \
        MFMA3(0, xh0, xh1, xl0, xl1);                                         \
        TRQ(xh0, xh1, xl0, xl1, trb + 3072u);                                 \
        WAIT8;                                                                \
        MFMA3(1, yh0, yh1, yl0, yl1);                                         \
        TRQ(yh0, yh1, yl0, yl1, trb + 4096u);                                 \
        WAIT8;                                                                \
        MFMA3(2, zh0, zh1, zl0, zl1);                                         \
        TRQ(zh0, zh1, zl0, zl1, trb + 5120u);                                 \
        WAIT8;                                                                \
        MFMA3(3, xh0, xh1, xl0, xl1);                                         \
        WAIT4;                                                                \
        MFMA3(4, yh0, yh1, yl0, yl1);                                         \
        WAIT0;                                                                \
        MFMA3(5, zh0, zh1, zl0, zl1);                                         \
        __builtin_amdgcn_s_setprio(0);                                        \
    } while (0)

    // prologue: chunk0 FB -> buf0; desc chunks 0,1 in reg sets A,B
    LOADFB(0);
    LOADDESC(A, 0);
    LOADDESC(B, CCH);
    WRITEFB(0);
    __syncthreads();

#pragma unroll 1
    for (int tp = 0; tp < 8; ++tp) {
        const int t0 = 2 * tp, t1 = 2 * tp + 1;
        // iter t0 (even chunk, buf0, desc set A)
        LOADFB((t0 + 1) * CCH);                // chunk t0+1 (t0+1 <= 15)
        COMPUTE(0, A);
        if (t0 + 2 < 16) LOADDESC(A, (t0 + 2) * CCH);
        WRITEFB(BUFHW);                        // chunk t0+1 -> buf1
        __syncthreads();
        // iter t1 (odd chunk, buf1, desc set B)
        if (t1 + 1 < 16) LOADFB((t1 + 1) * CCH);
        COMPUTE(BUFHW, B);
        if (t1 + 2 < 16) LOADDESC(B, (t1 + 2) * CCH);
        if (t1 + 1 < 16) WRITEFB(0);
        __syncthreads();
    }

    // ---- epilogue (buf0 dead: floats 0..1631 reused as scratch) ----
    float* fscr = (float*)&smem_us[0];
    if (tid < 192) {
        *(float4*)&fscr[scb * 96 + so * 8]     = make_float4(sq[0], sq[1], sq[2], sq[3]);
        *(float4*)&fscr[scb * 96 + so * 8 + 4] = make_float4(sq[4], sq[5], sq[6], sq[7]);
    }
    __syncthreads();
    if (tid < 96) {
        float s = 0.f;
#pragma unroll
        for (int g = 0; g < 16; ++g) s += fscr[g * 96 + tid];
        fscr[1536 + tid] = s;
    }
    __syncthreads();

    const float inv2048 = 1.f / 2048.f;
#pragma unroll
    for (int r = 0; r < 4; ++r) {
        float bv = 1e30f; int bn = 1 << 28;
#pragma unroll
        for (int nt = 0; nt < 6; ++nt) {       // nt ascending -> n ascending
            float cross = accH[nt][r] + accX[nt][r] * inv2048;
            float d = fscr[1536 + nt * 16 + (l & 15)] - 2.f * cross;
            int n = nb + nt * 16 + (l & 15);
            if (d < bv) { bv = d; bn = n; }
        }
#pragma unroll
        for (int m = 1; m < 16; m <<= 1) {     // reduce the 16 n-lanes
            float ov = __shfl_xor(bv, m);
            int   on = __shfl_xor(bn, m);
            if (ov < bv || (ov == bv && on < bn)) { bv = ov; bn = on; }
        }
        if ((l & 15) == 0) {
            int k = w * 16 + (l >> 4) * 4 + r;
            unsigned bits = __float_as_uint(bv);
            unsigned key = (bits & 0x80000000u) ? ~bits : (bits | 0x80000000u);
            u64 packed = ((u64)key << 32) | (unsigned)bn;
            atomicMin(&slots[b * K_ + k], packed);   // order-independent, exact ties
        }
    }
#undef LOADFB
#undef LOADDESC
#undef CVT8
#undef WRITEFB
#undef TRQ
#undef WAIT8
#undef WAIT4
#undef WAIT0
#undef MFMA3
#undef COMPUTE
}

// ---------------- kernel 4: decode slots + offsets + mode ----------------
__global__ void k_redmode(const u64* __restrict__ slots,
                          const int* __restrict__ rowA, const int* __restrict__ colA,
                          int* __restrict__ out) {
    __shared__ int r_s[64], c_s[64];
    int b = blockIdx.x, k = threadIdx.x;
    u64 s = slots[b * K_ + k];
    int bn = (int)(unsigned)(s & 0xFFFFFFFFull);
    int rB = bn / W_, cB = bn - rB * W_;
    r_s[k] = rowA[b * K_ + k] - rB;
    c_s[k] = colA[b * K_ + k] - cB;
    __syncthreads();
    int mr = r_s[k], mc = c_s[k], cnt = 0;
#pragma unroll
    for (int j = 0; j < 64; ++j) cnt += (r_s[j] == mr && c_s[j] == mc) ? 1 : 0;
    int bk = k, bc = cnt;
    for (int m = 1; m < 64; m <<= 1) {
        int oc = __shfl_xor(bc, m);
        int ok = __shfl_xor(bk, m);
        if (oc > bc || (oc == bc && ok < bk)) { bc = oc; bk = ok; }
    }
    if (k == 0) { out[b * 2] = r_s[bk]; out[b * 2 + 1] = c_s[bk]; }
}

extern "C" void kernel_launch(void* const* d_in, const int* in_sizes, int n_in,
                              void* d_out, int out_size, void* d_ws, size_t ws_size,
                              hipStream_t stream) {
    const float* A  = (const float*)d_in[0];
    const float* FB = (const float*)d_in[1];
    char* ws = (char*)d_ws;
    float*     part  = (float*)(ws + OFF_PARTIAL);
    _Float16*  descH = (_Float16*)(ws + OFF_DESCH);
    _Float16*  descL = (_Float16*)(ws + OFF_DESCL);
    int*       rowA  = (int*)(ws + OFF_ROWA);
    int*       colA  = (int*)(ws + OFF_COLA);
    u64*       slots = (u64*)(ws + OFF_SLOTS);
    int*       out   = (int*)d_out;

    k_partial<<<dim3((B_ * HW) / 1024, 8), 256, 0, stream>>>(A, part, slots);
    k_selgather<<<dim3(K_, B_), 64, 0, stream>>>(part, A, rowA, colA, descH, descL);
    k_main<<<dim3(NBLK, B_), 256, 0, stream>>>(FB, descH, descL, slots);
    k_redmode<<<dim3(B_), 64, 0, stream>>>(slots, rowA, colA, out);
}